// Round 1
// baseline (2391.555 us; speedup 1.0000x reference)
//
#include <hip/hip_runtime.h>
#include <hip/hip_bf16.h>
#include <math.h>

// Problem constants
#define Bn 2
#define Tn 2048
#define Cn 768
#define Hn 12
#define HDn 64
#define D2n 32
#define FFn 3072
#define EPSn 1e-5f

// ---------------- RMSNorm: one block per row (C=768, 256 threads) ----------------
__global__ __launch_bounds__(256) void rmsnorm_kernel(const float* __restrict__ x,
                                                      const float* __restrict__ g,
                                                      float* __restrict__ out) {
    int row = blockIdx.x;                 // 0 .. B*T-1
    const float* xr = x + (size_t)row * Cn;
    float* orow = out + (size_t)row * Cn;
    int tid = threadIdx.x;
    float v[3];
    float ss = 0.f;
#pragma unroll
    for (int i = 0; i < 3; ++i) {
        v[i] = xr[tid + 256 * i];
        ss += v[i] * v[i];
    }
    // wave (64-lane) butterfly reduce
#pragma unroll
    for (int o = 32; o; o >>= 1) ss += __shfl_xor(ss, o);
    __shared__ float red[4];
    int w = tid >> 6;
    if ((tid & 63) == 0) red[w] = ss;
    __syncthreads();
    float tot = red[0] + red[1] + red[2] + red[3];
    float s = rsqrtf(tot / (float)Cn + EPSn);
#pragma unroll
    for (int i = 0; i < 3; ++i) {
        int c = tid + 256 * i;
        orow[c] = g[c] * v[i] * s;
    }
}

// ---------------- Tiled fp32 GEMM: C[M,N] = A[M,K] @ B[K,N] (+ epilogue) --------
// EPI: 0 = none, 1 = += residual, 2 = relu^2
// 64x64 tile, 256 threads, each thread 4x4, K-step 16.
template <int EPI>
__global__ __launch_bounds__(256) void gemm64(const float* __restrict__ A,
                                              const float* __restrict__ B,
                                              const float* __restrict__ R,
                                              float* __restrict__ C,
                                              int M, int N, int K) {
    __shared__ float As[16][66];
    __shared__ float Bs[16][66];
    int tid = threadIdx.x;
    int tx = tid & 15, ty = tid >> 4;
    int bn = blockIdx.x * 64, bm = blockIdx.y * 64;
    int ar = tid >> 2, ac = (tid & 3) << 2;   // A: row 0..63, col 0..12 step 4
    int br = tid >> 4, bc = (tid & 15) << 2;  // B: row 0..15, col 0..60 step 4
    float acc[4][4] = {};

    for (int k0 = 0; k0 < K; k0 += 16) {
        float4 av = *(const float4*)(A + (size_t)(bm + ar) * K + k0 + ac);
        float4 bv = *(const float4*)(B + (size_t)(k0 + br) * N + bn + bc);
        As[ac + 0][ar] = av.x;
        As[ac + 1][ar] = av.y;
        As[ac + 2][ar] = av.z;
        As[ac + 3][ar] = av.w;
        Bs[br][bc + 0] = bv.x;
        Bs[br][bc + 1] = bv.y;
        Bs[br][bc + 2] = bv.z;
        Bs[br][bc + 3] = bv.w;
        __syncthreads();
#pragma unroll
        for (int kk = 0; kk < 16; ++kk) {
            float a[4], b[4];
#pragma unroll
            for (int i = 0; i < 4; ++i) a[i] = As[kk][ty * 4 + i];
#pragma unroll
            for (int j = 0; j < 4; ++j) b[j] = Bs[kk][tx * 4 + j];
#pragma unroll
            for (int i = 0; i < 4; ++i)
#pragma unroll
                for (int j = 0; j < 4; ++j) acc[i][j] += a[i] * b[j];
        }
        __syncthreads();
    }
#pragma unroll
    for (int i = 0; i < 4; ++i) {
        int row = bm + ty * 4 + i;
#pragma unroll
        for (int j = 0; j < 4; ++j) {
            int col = bn + tx * 4 + j;
            float c = acc[i][j];
            if (EPI == 1) c += R[(size_t)row * N + col];
            if (EPI == 2) {
                c = fmaxf(c, 0.f);
                c = c * c;
            }
            C[(size_t)row * N + col] = c;
        }
    }
}

// ---------------- RoPE (in-place on q and k) ------------------------------------
__global__ __launch_bounds__(256) void rope_kernel(float* __restrict__ q,
                                                   float* __restrict__ k,
                                                   const float* __restrict__ cosp,
                                                   const float* __restrict__ sinp,
                                                   int n) {
    int idx = blockIdx.x * 256 + threadIdx.x;  // over B*T*H*D2
    if (idx >= n) return;
    int i = idx & (D2n - 1);
    int bth = idx >> 5;                 // ((b*T)+t)*H + h
    int t = (bth / Hn) % Tn;
    size_t base = (size_t)bth * HDn;
    float c = cosp[t * D2n + i], s = sinp[t * D2n + i];
    float x1 = q[base + i], x2 = q[base + D2n + i];
    q[base + i] = x1 * c + x2 * s;
    q[base + D2n + i] = -x1 * s + x2 * c;
    x1 = k[base + i];
    x2 = k[base + D2n + i];
    k[base + i] = x1 * c + x2 * s;
    k[base + D2n + i] = -x1 * s + x2 * c;
}

// ---------------- Causal flash attention ----------------------------------------
// Block = 256 threads = 4 waves; wave w handles query row qt*4+w of one (b,h).
// K/V staged in 64-row LDS chunks shared by the 4 waves.
__global__ __launch_bounds__(256) void attn_kernel(const float* __restrict__ q,
                                                   const float* __restrict__ k,
                                                   const float* __restrict__ v,
                                                   float* __restrict__ y) {
    __shared__ float sk[64][65];
    __shared__ float sv[64][65];
    __shared__ float sq[4][64];
    int blk = blockIdx.x;
    int qt = blk & 511;       // T/4 = 512 query tiles
    int bh = blk >> 9;
    int h = bh % Hn;
    int b = bh / Hn;
    int w = threadIdx.x >> 6, lane = threadIdx.x & 63;
    int qidx = qt * 4 + w;
    size_t qoff = ((size_t)(b * Tn + qidx) * Hn + h) * HDn + lane;
    float qv = q[qoff];
    sq[w][lane] = qv;

    float m = -INFINITY, l = 0.f, acc = 0.f;
    int qmax = qt * 4 + 3;
    const float scale = 0.125f;  // 1/sqrt(64)

    for (int t0 = 0; t0 <= qmax; t0 += 64) {
        __syncthreads();  // protects LDS reuse; also publishes sq on first iter
#pragma unroll
        for (int r = 0; r < 16; ++r) {
            int i = threadIdx.x + 256 * r;  // 0..4095
            int j = i >> 6, d = i & 63;
            size_t goff = ((size_t)(b * Tn + t0 + j) * Hn + h) * HDn + d;
            sk[j][d] = k[goff];
            sv[j][d] = v[goff];
        }
        __syncthreads();
        int nk = qidx - t0 + 1;
        if (nk > 64) nk = 64;
        if (nk > 0) {
            float s = -INFINITY;
            if (lane < nk) {
                float ds = 0.f;
#pragma unroll
                for (int d = 0; d < 64; ++d) ds += sq[w][d] * sk[lane][d];
                s = ds * scale;
            }
            float mx = s;
#pragma unroll
            for (int o = 32; o; o >>= 1) mx = fmaxf(mx, __shfl_xor(mx, o));
            float mn = fmaxf(m, mx);
            float p = (lane < nk) ? __expf(s - mn) : 0.f;
            float ps = p;
#pragma unroll
            for (int o = 32; o; o >>= 1) ps += __shfl_xor(ps, o);
            float alpha = __expf(m - mn);
            l = l * alpha + ps;
            acc *= alpha;
#pragma unroll
            for (int j = 0; j < 64; ++j) acc += __shfl(p, j) * sv[j][lane];
            m = mn;
        }
    }
    y[qoff] = acc / l;
}

// ---------------- launch ---------------------------------------------------------
extern "C" void kernel_launch(void* const* d_in, const int* in_sizes, int n_in,
                              void* d_out, int out_size, void* d_ws, size_t ws_size,
                              hipStream_t stream) {
    const float* x    = (const float*)d_in[0];
    const float* cosp = (const float*)d_in[1];
    const float* sinp = (const float*)d_in[2];
    const float* wq   = (const float*)d_in[3];
    const float* wk   = (const float*)d_in[4];
    const float* wv   = (const float*)d_in[5];
    const float* wo   = (const float*)d_in[6];
    const float* wfc  = (const float*)d_in[7];
    const float* wpr  = (const float*)d_in[8];
    const float* g1   = (const float*)d_in[9];
    const float* g2   = (const float*)d_in[10];
    float* out = (float*)d_out;

    const size_t S = (size_t)Bn * Tn * Cn;  // 4096*768
    float* W = (float*)d_ws;
    float* h  = W;          // S
    float* qb = W + S;      // S
    float* kb = W + 2 * S;  // S
    float* vb = W + 3 * S;  // S
    float* yb = W + 4 * S;  // S
    float* x1 = W + 5 * S;  // S
    float* f  = W + S;      // 4S, reuses q..y after attention
    float* h2 = W;          // reuses h

    const int M = Bn * Tn;  // 4096

    // 1. h = rmsnorm(x, g1)
    rmsnorm_kernel<<<M, 256, 0, stream>>>(x, g1, h);

    // 2. q,k,v projections
    dim3 g768(Cn / 64, M / 64);
    gemm64<0><<<g768, 256, 0, stream>>>(h, wq, nullptr, qb, M, Cn, Cn);
    gemm64<0><<<g768, 256, 0, stream>>>(h, wk, nullptr, kb, M, Cn, Cn);
    gemm64<0><<<g768, 256, 0, stream>>>(h, wv, nullptr, vb, M, Cn, Cn);

    // 3. RoPE in-place on q, k
    int nrope = Bn * Tn * Hn * D2n;
    rope_kernel<<<(nrope + 255) / 256, 256, 0, stream>>>(qb, kb, cosp, sinp, nrope);

    // 4. attention -> y
    attn_kernel<<<Bn * Hn * (Tn / 4), 256, 0, stream>>>(qb, kb, vb, yb);

    // 5. x1 = x + y @ wo
    gemm64<1><<<g768, 256, 0, stream>>>(yb, wo, x, x1, M, Cn, Cn);

    // 6. h2 = rmsnorm(x1, g2)
    rmsnorm_kernel<<<M, 256, 0, stream>>>(x1, g2, h2);

    // 7. f = relu(h2 @ wfc)^2
    dim3 gff(FFn / 64, M / 64);
    gemm64<2><<<gff, 256, 0, stream>>>(h2, wfc, nullptr, f, M, FFn, Cn);

    // 8. out = x1 + f @ wpr
    gemm64<1><<<g768, 256, 0, stream>>>(f, wpr, x1, out, M, Cn, FFn);
}

// Round 3
// 1175.597 us; speedup vs baseline: 2.0343x; 2.0343x over previous
//
#include <hip/hip_runtime.h>
#include <hip/hip_bf16.h>
#include <math.h>

// Problem constants
#define Bn 2
#define Tn 2048
#define Cn 768
#define Hn 12
#define HDn 64
#define D2n 32
#define FFn 3072
#define EPSn 1e-5f

typedef short s16x4 __attribute__((ext_vector_type(4)));
typedef short s16x8 __attribute__((ext_vector_type(8)));
typedef float f32x4 __attribute__((ext_vector_type(4)));

__device__ __forceinline__ unsigned short f2bf(float f) {
    union { float f; unsigned u; } v;
    v.f = f;
    unsigned r = (v.u + 0x7fffu + ((v.u >> 16) & 1u)) >> 16;
    return (unsigned short)r;
}

// ---------------- RMSNorm: one block per row (C=768, 256 threads) ----------------
__global__ __launch_bounds__(256) void rmsnorm_kernel(const float* __restrict__ x,
                                                      const float* __restrict__ g,
                                                      float* __restrict__ out) {
    int row = blockIdx.x;
    const float* xr = x + (size_t)row * Cn;
    float* orow = out + (size_t)row * Cn;
    int tid = threadIdx.x;
    float v[3];
    float ss = 0.f;
#pragma unroll
    for (int i = 0; i < 3; ++i) {
        v[i] = xr[tid + 256 * i];
        ss += v[i] * v[i];
    }
#pragma unroll
    for (int o = 32; o; o >>= 1) ss += __shfl_xor(ss, o);
    __shared__ float red[4];
    int w = tid >> 6;
    if ((tid & 63) == 0) red[w] = ss;
    __syncthreads();
    float tot = red[0] + red[1] + red[2] + red[3];
    float s = rsqrtf(tot / (float)Cn + EPSn);
#pragma unroll
    for (int i = 0; i < 3; ++i) {
        int c = tid + 256 * i;
        orow[c] = g[c] * v[i] * s;
    }
}

// ---------------- Tiled fp32 GEMM: C[M,N] = A[M,K] @ B[K,N] (+ epilogue) --------
// EPI: 0 = none, 1 = += residual, 2 = relu^2
template <int EPI>
__global__ __launch_bounds__(256) void gemm64(const float* __restrict__ A,
                                              const float* __restrict__ B,
                                              const float* __restrict__ R,
                                              float* __restrict__ C,
                                              int M, int N, int K) {
    __shared__ float As[16][66];
    __shared__ float Bs[16][66];
    int tid = threadIdx.x;
    int tx = tid & 15, ty = tid >> 4;
    int bn = blockIdx.x * 64, bm = blockIdx.y * 64;
    int ar = tid >> 2, ac = (tid & 3) << 2;
    int br = tid >> 4, bc = (tid & 15) << 2;
    float acc[4][4] = {};

    for (int k0 = 0; k0 < K; k0 += 16) {
        float4 av = *(const float4*)(A + (size_t)(bm + ar) * K + k0 + ac);
        float4 bv = *(const float4*)(B + (size_t)(k0 + br) * N + bn + bc);
        As[ac + 0][ar] = av.x;
        As[ac + 1][ar] = av.y;
        As[ac + 2][ar] = av.z;
        As[ac + 3][ar] = av.w;
        Bs[br][bc + 0] = bv.x;
        Bs[br][bc + 1] = bv.y;
        Bs[br][bc + 2] = bv.z;
        Bs[br][bc + 3] = bv.w;
        __syncthreads();
#pragma unroll
        for (int kk = 0; kk < 16; ++kk) {
            float a[4], b[4];
#pragma unroll
            for (int i = 0; i < 4; ++i) a[i] = As[kk][ty * 4 + i];
#pragma unroll
            for (int j = 0; j < 4; ++j) b[j] = Bs[kk][tx * 4 + j];
#pragma unroll
            for (int i = 0; i < 4; ++i)
#pragma unroll
                for (int j = 0; j < 4; ++j) acc[i][j] += a[i] * b[j];
        }
        __syncthreads();
    }
#pragma unroll
    for (int i = 0; i < 4; ++i) {
        int row = bm + ty * 4 + i;
#pragma unroll
        for (int j = 0; j < 4; ++j) {
            int col = bn + tx * 4 + j;
            float c = acc[i][j];
            if (EPI == 1) c += R[(size_t)row * N + col];
            if (EPI == 2) {
                c = fmaxf(c, 0.f);
                c = c * c;
            }
            C[(size_t)row * N + col] = c;
        }
    }
}

// ---------------- RoPE (in-place on q and k) ------------------------------------
__global__ __launch_bounds__(256) void rope_kernel(float* __restrict__ q,
                                                   float* __restrict__ k,
                                                   const float* __restrict__ cosp,
                                                   const float* __restrict__ sinp,
                                                   int n) {
    int idx = blockIdx.x * 256 + threadIdx.x;
    if (idx >= n) return;
    int i = idx & (D2n - 1);
    int bth = idx >> 5;
    int t = (bth / Hn) % Tn;
    size_t base = (size_t)bth * HDn;
    float c = cosp[t * D2n + i], s = sinp[t * D2n + i];
    float x1 = q[base + i], x2 = q[base + D2n + i];
    q[base + i] = x1 * c + x2 * s;
    q[base + D2n + i] = -x1 * s + x2 * c;
    x1 = k[base + i];
    x2 = k[base + D2n + i];
    k[base + i] = x1 * c + x2 * s;
    k[base + D2n + i] = -x1 * s + x2 * c;
}

// ---------------- MFMA causal flash attention (S^T register trick) ---------------
// Block = 256 thr = 4 waves, 64-query tile; wave w owns queries w*16..w*16+15.
// S^T = K @ Q^T so P stays in registers as the PV A-operand (permuted-k trick);
// no P LDS round-trip, no inline waitcnt. One (m,l) per lane (query = lane&15).
#define ATT_PAD 72

__global__ __launch_bounds__(256) void attn_mfma_kernel(const float* __restrict__ q,
                                                        const float* __restrict__ k,
                                                        const float* __restrict__ v,
                                                        float* __restrict__ y) {
    __shared__ unsigned short sQ[64 * ATT_PAD];
    __shared__ unsigned short sK[64 * ATT_PAD];
    __shared__ unsigned short sVt[64 * ATT_PAD];

    const int nqt = Tn / 64;  // 32
    int qt = blockIdx.x & (nqt - 1);
    int bh = blockIdx.x / nqt;
    int h = bh % Hn;
    int b = bh / Hn;
    int qbase = qt * 64;
    int tid = threadIdx.x;
    int lane = tid & 63;
    int w = tid >> 6;
    int quad = lane >> 4;
    int l16 = lane & 15;

    const int strideT = Hn * HDn;  // 768
    const float* qg = q + ((size_t)(b * Tn) * Hn + h) * HDn;
    const float* kg = k + ((size_t)(b * Tn) * Hn + h) * HDn;
    const float* vg = v + ((size_t)(b * Tn) * Hn + h) * HDn;

    // stage Q tile (64 rows x 64 d) as bf16
#pragma unroll
    for (int r = 0; r < 4; ++r) {
        int idx = tid + 256 * r;
        int row = idx >> 4;
        int dg = (idx & 15) * 4;
        float4 qv = *(const float4*)(qg + (size_t)(qbase + row) * strideT + dg);
        ushort4 u;
        u.x = f2bf(qv.x); u.y = f2bf(qv.y); u.z = f2bf(qv.z); u.w = f2bf(qv.w);
        *(ushort4*)&sQ[row * ATT_PAD + dg] = u;
    }
    __syncthreads();

    // Q fragment (B operand of S^T): B[k=d=quad*8+j][n=query=l16]
    s16x8 qf0 = *(const s16x8*)&sQ[(w * 16 + l16) * ATT_PAD + quad * 8];
    s16x8 qf1 = *(const s16x8*)&sQ[(w * 16 + l16) * ATT_PAD + 32 + quad * 8];

    f32x4 acc[4];
#pragma unroll
    for (int i = 0; i < 4; ++i) acc[i] = (f32x4){0.f, 0.f, 0.f, 0.f};
    float m = -3e38f, l = 0.f;  // per-lane: query = qbase + w*16 + l16

    const float scale = 0.125f;  // 1/sqrt(64)
    const int qloc = w * 16 + l16;

    for (int kbase = 0; kbase <= qbase; kbase += 64) {
        __syncthreads();  // prior chunk's LDS reads complete before restage
#pragma unroll
        for (int r = 0; r < 4; ++r) {
            int idx = tid + 256 * r;
            int row = idx >> 4;
            int dg = (idx & 15) * 4;
            float4 kv = *(const float4*)(kg + (size_t)(kbase + row) * strideT + dg);
            ushort4 u;
            u.x = f2bf(kv.x); u.y = f2bf(kv.y); u.z = f2bf(kv.z); u.w = f2bf(kv.w);
            *(ushort4*)&sK[row * ATT_PAD + dg] = u;
        }
#pragma unroll
        for (int r = 0; r < 4; ++r) {
            int idx = tid + 256 * r;
            int key = idx & 63;
            int dg = (idx >> 6) * 4;
            float4 vv = *(const float4*)(vg + (size_t)(kbase + key) * strideT + dg);
            sVt[(dg + 0) * ATT_PAD + key] = f2bf(vv.x);
            sVt[(dg + 1) * ATT_PAD + key] = f2bf(vv.y);
            sVt[(dg + 2) * ATT_PAD + key] = f2bf(vv.z);
            sVt[(dg + 3) * ATT_PAD + key] = f2bf(vv.w);
        }
        __syncthreads();

        const bool diag = (kbase == qbase);

        // S^T = K @ Q^T : C[row=key_local=quad*4+rg][col=query=l16]
        f32x4 st[4];
#pragma unroll
        for (int kb = 0; kb < 4; ++kb) {
            s16x8 kf0 = *(const s16x8*)&sK[(kb * 16 + l16) * ATT_PAD + quad * 8];
            s16x8 kf1 = *(const s16x8*)&sK[(kb * 16 + l16) * ATT_PAD + 32 + quad * 8];
            f32x4 c = (f32x4){0.f, 0.f, 0.f, 0.f};
            c = __builtin_amdgcn_mfma_f32_16x16x32_bf16(kf0, qf0, c, 0, 0, 0);
            c = __builtin_amdgcn_mfma_f32_16x16x32_bf16(kf1, qf1, c, 0, 0, 0);
            st[kb] = c;
        }

        // scale + causal mask (key_local = kb*16 + quad*4 + rg; masked iff > qloc
        // on the diagonal chunk; non-diag chunks are fully unmasked)
#pragma unroll
        for (int kb = 0; kb < 4; ++kb) {
#pragma unroll
            for (int rg = 0; rg < 4; ++rg) {
                float s = st[kb][rg] * scale;
                if (diag && (kb * 16 + quad * 4 + rg > qloc)) s = -1e30f;
                st[kb][rg] = s;
            }
        }

        // online softmax per query (lane l16), replicated across quads
        float mx = -3e38f;
#pragma unroll
        for (int kb = 0; kb < 4; ++kb)
#pragma unroll
            for (int rg = 0; rg < 4; ++rg) mx = fmaxf(mx, st[kb][rg]);
        mx = fmaxf(mx, __shfl_xor(mx, 16));
        mx = fmaxf(mx, __shfl_xor(mx, 32));
        float mnew = fmaxf(m, mx);
        float alpha = __expf(m - mnew);
        m = mnew;
        float t = 0.f;
#pragma unroll
        for (int kb = 0; kb < 4; ++kb) {
#pragma unroll
            for (int rg = 0; rg < 4; ++rg) {
                float p = __expf(st[kb][rg] - mnew);
                st[kb][rg] = p;
                t += p;
            }
        }
        t += __shfl_xor(t, 16);
        t += __shfl_xor(t, 32);
        l = l * alpha + t;

        // rescale acc rows (acc row = query_local quad*4+rg) by that query's alpha
        float aq[4];
#pragma unroll
        for (int rg = 0; rg < 4; ++rg) aq[rg] = __shfl(alpha, quad * 4 + rg);
#pragma unroll
        for (int db = 0; db < 4; ++db)
#pragma unroll
            for (int rg = 0; rg < 4; ++rg) acc[db][rg] *= aq[rg];

        // P fragments straight from registers.
        // k-slot permutation: k=quad*8+j <-> key = (j<4 ? quad*4+j : 16+quad*4+j-4)
        // (+32 for the second MFMA); V fragment uses the same permutation.
        s16x8 pa0, pa1;
#pragma unroll
        for (int j = 0; j < 4; ++j) {
            pa0[j]     = (short)f2bf(st[0][j]);
            pa0[4 + j] = (short)f2bf(st[1][j]);
            pa1[j]     = (short)f2bf(st[2][j]);
            pa1[4 + j] = (short)f2bf(st[3][j]);
        }

        // O += P @ V  (D[m=query][n=d], C row = quad*4+rg = query_local)
#pragma unroll
        for (int db = 0; db < 4; ++db) {
            int r = db * 16 + l16;
            s16x4 a0 = *(const s16x4*)&sVt[r * ATT_PAD + quad * 4];
            s16x4 a1 = *(const s16x4*)&sVt[r * ATT_PAD + 16 + quad * 4];
            s16x4 b0 = *(const s16x4*)&sVt[r * ATT_PAD + 32 + quad * 4];
            s16x4 b1 = *(const s16x4*)&sVt[r * ATT_PAD + 48 + quad * 4];
            s16x8 vf0, vf1;
#pragma unroll
            for (int j = 0; j < 4; ++j) {
                vf0[j] = a0[j]; vf0[4 + j] = a1[j];
                vf1[j] = b0[j]; vf1[4 + j] = b1[j];
            }
            acc[db] = __builtin_amdgcn_mfma_f32_16x16x32_bf16(pa0, vf0, acc[db], 0, 0, 0);
            acc[db] = __builtin_amdgcn_mfma_f32_16x16x32_bf16(pa1, vf1, acc[db], 0, 0, 0);
        }
    }

    // epilogue: row = qbase + w*16 + quad*4 + rg, col = db*16 + l16
    float lq[4];
#pragma unroll
    for (int rg = 0; rg < 4; ++rg) lq[rg] = __shfl(l, quad * 4 + rg);
#pragma unroll
    for (int db = 0; db < 4; ++db) {
#pragma unroll
        for (int rg = 0; rg < 4; ++rg) {
            int row = qbase + w * 16 + quad * 4 + rg;
            y[((size_t)(b * Tn + row) * Hn + h) * HDn + db * 16 + l16] =
                acc[db][rg] / lq[rg];
        }
    }
}

// ---------------- launch ---------------------------------------------------------
extern "C" void kernel_launch(void* const* d_in, const int* in_sizes, int n_in,
                              void* d_out, int out_size, void* d_ws, size_t ws_size,
                              hipStream_t stream) {
    const float* x    = (const float*)d_in[0];
    const float* cosp = (const float*)d_in[1];
    const float* sinp = (const float*)d_in[2];
    const float* wq   = (const float*)d_in[3];
    const float* wk   = (const float*)d_in[4];
    const float* wv   = (const float*)d_in[5];
    const float* wo   = (const float*)d_in[6];
    const float* wfc  = (const float*)d_in[7];
    const float* wpr  = (const float*)d_in[8];
    const float* g1   = (const float*)d_in[9];
    const float* g2   = (const float*)d_in[10];
    float* out = (float*)d_out;

    const size_t S = (size_t)Bn * Tn * Cn;
    float* W = (float*)d_ws;
    float* h  = W;
    float* qb = W + S;
    float* kb = W + 2 * S;
    float* vb = W + 3 * S;
    float* yb = W + 4 * S;
    float* x1 = W + 5 * S;
    float* f  = W + S;      // 4S, reuses q..y after attention
    float* h2 = W;          // reuses h

    const int M = Bn * Tn;  // 4096

    rmsnorm_kernel<<<M, 256, 0, stream>>>(x, g1, h);

    dim3 g768(Cn / 64, M / 64);
    gemm64<0><<<g768, 256, 0, stream>>>(h, wq, nullptr, qb, M, Cn, Cn);
    gemm64<0><<<g768, 256, 0, stream>>>(h, wk, nullptr, kb, M, Cn, Cn);
    gemm64<0><<<g768, 256, 0, stream>>>(h, wv, nullptr, vb, M, Cn, Cn);

    int nrope = Bn * Tn * Hn * D2n;
    rope_kernel<<<(nrope + 255) / 256, 256, 0, stream>>>(qb, kb, cosp, sinp, nrope);

    attn_mfma_kernel<<<Bn * Hn * (Tn / 64), 256, 0, stream>>>(qb, kb, vb, yb);

    gemm64<1><<<g768, 256, 0, stream>>>(yb, wo, x, x1, M, Cn, Cn);

    rmsnorm_kernel<<<M, 256, 0, stream>>>(x1, g2, h2);

    dim3 gff(FFn / 64, M / 64);
    gemm64<2><<<gff, 256, 0, stream>>>(h2, wfc, nullptr, f, M, FFn, Cn);

    gemm64<1><<<g768, 256, 0, stream>>>(f, wpr, x1, out, M, Cn, FFn);
}

// Round 4
// 396.654 us; speedup vs baseline: 6.0293x; 2.9638x over previous
//
#include <hip/hip_runtime.h>
#include <hip/hip_bf16.h>
#include <math.h>

// Problem constants
#define Bn 2
#define Tn 2048
#define Cn 768
#define Hn 12
#define HDn 64
#define D2n 32
#define FFn 3072
#define EPSn 1e-5f
#define QKVS (3 * Cn)  // 2304, row stride of fused qkv buffer

typedef short s16x4 __attribute__((ext_vector_type(4)));
typedef short s16x8 __attribute__((ext_vector_type(8)));
typedef float f32x4 __attribute__((ext_vector_type(4)));
typedef unsigned short u16;

__device__ __forceinline__ u16 f2bf(float f) {
    union { float f; unsigned u; } v;
    v.f = f;
    unsigned r = (v.u + 0x7fffu + ((v.u >> 16) & 1u)) >> 16;
    return (u16)r;
}

__device__ __forceinline__ void gl2lds16(const void* g, void* l) {
    __builtin_amdgcn_global_load_lds((const __attribute__((address_space(1))) void*)g,
                                     (__attribute__((address_space(3))) void*)l,
                                     16, 0, 0);
}

// ---------------- RMSNorm -> bf16 out: one block per row ------------------------
__global__ __launch_bounds__(256) void rmsnorm_bf16_kernel(const float* __restrict__ x,
                                                           const float* __restrict__ g,
                                                           u16* __restrict__ out) {
    int row = blockIdx.x;
    const float* xr = x + (size_t)row * Cn;
    u16* orow = out + (size_t)row * Cn;
    int tid = threadIdx.x;
    float v[3];
    float ss = 0.f;
#pragma unroll
    for (int i = 0; i < 3; ++i) {
        v[i] = xr[tid + 256 * i];
        ss += v[i] * v[i];
    }
#pragma unroll
    for (int o = 32; o; o >>= 1) ss += __shfl_xor(ss, o);
    __shared__ float red[4];
    int w = tid >> 6;
    if ((tid & 63) == 0) red[w] = ss;
    __syncthreads();
    float tot = red[0] + red[1] + red[2] + red[3];
    float s = rsqrtf(tot / (float)Cn + EPSn);
#pragma unroll
    for (int i = 0; i < 3; ++i) {
        int c = tid + 256 * i;
        orow[c] = f2bf(g[c] * v[i] * s);
    }
}

// ---------------- Weight transpose+convert: W[K][N] fp32 -> Wt[N][K] bf16 --------
__global__ __launch_bounds__(256) void transpose_bf16_kernel(const float* __restrict__ W,
                                                             u16* __restrict__ Wt,
                                                             int K, int N) {
    __shared__ u16 t[32][33];
    int bx = blockIdx.x * 32;  // n0
    int by = blockIdx.y * 32;  // k0
    int tx = threadIdx.x & 31, ty = threadIdx.x >> 5;  // ty 0..7
#pragma unroll
    for (int i = 0; i < 4; ++i) {
        int kk = by + ty + i * 8;
        t[ty + i * 8][tx] = f2bf(W[(size_t)kk * N + bx + tx]);
    }
    __syncthreads();
#pragma unroll
    for (int i = 0; i < 4; ++i) {
        int n = bx + ty + i * 8;
        Wt[(size_t)n * K + by + tx] = t[tx][ty + i * 8];
    }
}

// ---------------- bf16 MFMA GEMM: C[M][N] = A[M][K] @ Bt[N][K]^T (+ epilogue) ----
// m97 structure: 128 x (NI*32) tile, 256 thr = 4 waves, wave = 64 x (NI*16),
// BK=32, un-padded LDS staged with global_load_lds width=16.
// EPI: 0 = fp32 store, 1 = fp32 store + fp32 residual, 2 = relu^2 -> bf16 store
template <int EPI, int NI>
__global__ __launch_bounds__(256) void gemm_bt(const u16* __restrict__ A,
                                               const u16* __restrict__ Bt,
                                               const float* __restrict__ R,
                                               void* __restrict__ Cout,
                                               int M, int N, int K) {
    __shared__ u16 As[128 * 32];
    __shared__ u16 Bs[NI * 32 * 32];
    int tid = threadIdx.x;
    int w = tid >> 6, lane = tid & 63;
    int quad = lane >> 4, l16 = lane & 15;
    int bm = blockIdx.y * 128;
    int bn = blockIdx.x * (NI * 32);
    int wrow = (w & 1) * 64, wcol = (w >> 1) * (NI * 16);

    f32x4 acc[4][NI];
#pragma unroll
    for (int i = 0; i < 4; ++i)
#pragma unroll
        for (int j = 0; j < NI; ++j) acc[i][j] = (f32x4){0.f, 0.f, 0.f, 0.f};

    int srow = lane >> 2;          // 0..15 within wave's 16-row slab
    int scol = (lane & 3) * 8;     // bf16 col offset (16 B per lane)

    for (int k0 = 0; k0 < K; k0 += 32) {
        __syncthreads();  // prior iteration's LDS reads complete
#pragma unroll
        for (int r = 0; r < 2; ++r) {
            int row = r * 64 + w * 16 + srow;
            gl2lds16(A + (size_t)(bm + row) * K + k0 + scol, &As[(r * 64 + w * 16) * 32]);
        }
#pragma unroll
        for (int r = 0; r < NI / 2; ++r) {
            int row = r * 64 + w * 16 + srow;
            gl2lds16(Bt + (size_t)(bn + row) * K + k0 + scol, &Bs[(r * 64 + w * 16) * 32]);
        }
        __syncthreads();  // drains vmcnt (compiler emits vmcnt(0) before s_barrier)

        s16x8 af[4], bf[NI];
#pragma unroll
        for (int mi = 0; mi < 4; ++mi)
            af[mi] = *(const s16x8*)&As[(wrow + mi * 16 + l16) * 32 + quad * 8];
#pragma unroll
        for (int ni = 0; ni < NI; ++ni)
            bf[ni] = *(const s16x8*)&Bs[(wcol + ni * 16 + l16) * 32 + quad * 8];
#pragma unroll
        for (int mi = 0; mi < 4; ++mi)
#pragma unroll
            for (int ni = 0; ni < NI; ++ni)
                acc[mi][ni] = __builtin_amdgcn_mfma_f32_16x16x32_bf16(af[mi], bf[ni],
                                                                      acc[mi][ni], 0, 0, 0);
    }

    // epilogue: C row = bm + wrow + mi*16 + quad*4 + rg, col = bn + wcol + ni*16 + l16
#pragma unroll
    for (int mi = 0; mi < 4; ++mi) {
#pragma unroll
        for (int rg = 0; rg < 4; ++rg) {
            size_t row = bm + wrow + mi * 16 + quad * 4 + rg;
#pragma unroll
            for (int ni = 0; ni < NI; ++ni) {
                size_t idx = row * N + bn + wcol + ni * 16 + l16;
                float c = acc[mi][ni][rg];
                if (EPI == 0) {
                    ((float*)Cout)[idx] = c;
                } else if (EPI == 1) {
                    ((float*)Cout)[idx] = c + R[idx];
                } else {
                    c = fmaxf(c, 0.f);
                    ((u16*)Cout)[idx] = f2bf(c * c);
                }
            }
        }
    }
}

// ---------------- RoPE (in-place on fused qkv buffer) ---------------------------
__global__ __launch_bounds__(256) void rope_kernel(float* __restrict__ qkv,
                                                   const float* __restrict__ cosp,
                                                   const float* __restrict__ sinp,
                                                   int n) {
    int idx = blockIdx.x * 256 + threadIdx.x;
    if (idx >= n) return;
    int i = idx & (D2n - 1);
    int bth = idx >> 5;
    int row = bth / Hn;    // b*T + t
    int hh = bth % Hn;
    int t = row & (Tn - 1);
    size_t qbase = (size_t)row * QKVS + hh * HDn;
    float c = cosp[t * D2n + i], s = sinp[t * D2n + i];
    float x1 = qkv[qbase + i], x2 = qkv[qbase + D2n + i];
    qkv[qbase + i] = x1 * c + x2 * s;
    qkv[qbase + D2n + i] = -x1 * s + x2 * c;
    size_t kbase = qbase + Cn;
    x1 = qkv[kbase + i];
    x2 = qkv[kbase + D2n + i];
    qkv[kbase + i] = x1 * c + x2 * s;
    qkv[kbase + D2n + i] = -x1 * s + x2 * c;
}

// ---------------- MFMA causal flash attention (S^T register trick) ---------------
// Reads fused qkv fp32 (row stride 2304), writes y bf16 [B,T,H,HD].
#define ATT_PAD 72

__global__ __launch_bounds__(256) void attn_mfma_kernel(const float* __restrict__ qkv,
                                                        u16* __restrict__ y) {
    __shared__ u16 sQ[64 * ATT_PAD];
    __shared__ u16 sK[64 * ATT_PAD];
    __shared__ u16 sVt[64 * ATT_PAD];

    const int nqt = Tn / 64;  // 32
    int qt = blockIdx.x & (nqt - 1);
    int bh = blockIdx.x / nqt;
    int h = bh % Hn;
    int b = bh / Hn;
    int qbase = qt * 64;
    int tid = threadIdx.x;
    int lane = tid & 63;
    int w = tid >> 6;
    int quad = lane >> 4;
    int l16 = lane & 15;

    const float* qg = qkv + (size_t)(b * Tn) * QKVS + h * HDn;
    const float* kg = qg + Cn;
    const float* vg = qg + 2 * Cn;

    // stage Q tile (64 rows x 64 d) as bf16
#pragma unroll
    for (int r = 0; r < 4; ++r) {
        int idx = tid + 256 * r;
        int row = idx >> 4;
        int dg = (idx & 15) * 4;
        float4 qv = *(const float4*)(qg + (size_t)(qbase + row) * QKVS + dg);
        ushort4 u;
        u.x = f2bf(qv.x); u.y = f2bf(qv.y); u.z = f2bf(qv.z); u.w = f2bf(qv.w);
        *(ushort4*)&sQ[row * ATT_PAD + dg] = u;
    }
    __syncthreads();

    s16x8 qf0 = *(const s16x8*)&sQ[(w * 16 + l16) * ATT_PAD + quad * 8];
    s16x8 qf1 = *(const s16x8*)&sQ[(w * 16 + l16) * ATT_PAD + 32 + quad * 8];

    f32x4 acc[4];
#pragma unroll
    for (int i = 0; i < 4; ++i) acc[i] = (f32x4){0.f, 0.f, 0.f, 0.f};
    float m = -3e38f, l = 0.f;

    const float scale = 0.125f;
    const int qloc = w * 16 + l16;

    for (int kbase = 0; kbase <= qbase; kbase += 64) {
        __syncthreads();
#pragma unroll
        for (int r = 0; r < 4; ++r) {
            int idx = tid + 256 * r;
            int row = idx >> 4;
            int dg = (idx & 15) * 4;
            float4 kv = *(const float4*)(kg + (size_t)(kbase + row) * QKVS + dg);
            ushort4 u;
            u.x = f2bf(kv.x); u.y = f2bf(kv.y); u.z = f2bf(kv.z); u.w = f2bf(kv.w);
            *(ushort4*)&sK[row * ATT_PAD + dg] = u;
        }
#pragma unroll
        for (int r = 0; r < 4; ++r) {
            int idx = tid + 256 * r;
            int key = idx & 63;
            int dg = (idx >> 6) * 4;
            float4 vv = *(const float4*)(vg + (size_t)(kbase + key) * QKVS + dg);
            sVt[(dg + 0) * ATT_PAD + key] = f2bf(vv.x);
            sVt[(dg + 1) * ATT_PAD + key] = f2bf(vv.y);
            sVt[(dg + 2) * ATT_PAD + key] = f2bf(vv.z);
            sVt[(dg + 3) * ATT_PAD + key] = f2bf(vv.w);
        }
        __syncthreads();

        const bool diag = (kbase == qbase);

        f32x4 st[4];
#pragma unroll
        for (int kb = 0; kb < 4; ++kb) {
            s16x8 kf0 = *(const s16x8*)&sK[(kb * 16 + l16) * ATT_PAD + quad * 8];
            s16x8 kf1 = *(const s16x8*)&sK[(kb * 16 + l16) * ATT_PAD + 32 + quad * 8];
            f32x4 c = (f32x4){0.f, 0.f, 0.f, 0.f};
            c = __builtin_amdgcn_mfma_f32_16x16x32_bf16(kf0, qf0, c, 0, 0, 0);
            c = __builtin_amdgcn_mfma_f32_16x16x32_bf16(kf1, qf1, c, 0, 0, 0);
            st[kb] = c;
        }

#pragma unroll
        for (int kb = 0; kb < 4; ++kb) {
#pragma unroll
            for (int rg = 0; rg < 4; ++rg) {
                float s = st[kb][rg] * scale;
                if (diag && (kb * 16 + quad * 4 + rg > qloc)) s = -1e30f;
                st[kb][rg] = s;
            }
        }

        float mx = -3e38f;
#pragma unroll
        for (int kb = 0; kb < 4; ++kb)
#pragma unroll
            for (int rg = 0; rg < 4; ++rg) mx = fmaxf(mx, st[kb][rg]);
        mx = fmaxf(mx, __shfl_xor(mx, 16));
        mx = fmaxf(mx, __shfl_xor(mx, 32));
        float mnew = fmaxf(m, mx);
        float alpha = __expf(m - mnew);
        m = mnew;
        float t = 0.f;
#pragma unroll
        for (int kb = 0; kb < 4; ++kb) {
#pragma unroll
            for (int rg = 0; rg < 4; ++rg) {
                float p = __expf(st[kb][rg] - mnew);
                st[kb][rg] = p;
                t += p;
            }
        }
        t += __shfl_xor(t, 16);
        t += __shfl_xor(t, 32);
        l = l * alpha + t;

        float aq[4];
#pragma unroll
        for (int rg = 0; rg < 4; ++rg) aq[rg] = __shfl(alpha, quad * 4 + rg);
#pragma unroll
        for (int db = 0; db < 4; ++db)
#pragma unroll
            for (int rg = 0; rg < 4; ++rg) acc[db][rg] *= aq[rg];

        s16x8 pa0, pa1;
#pragma unroll
        for (int j = 0; j < 4; ++j) {
            pa0[j]     = (short)f2bf(st[0][j]);
            pa0[4 + j] = (short)f2bf(st[1][j]);
            pa1[j]     = (short)f2bf(st[2][j]);
            pa1[4 + j] = (short)f2bf(st[3][j]);
        }

#pragma unroll
        for (int db = 0; db < 4; ++db) {
            int r = db * 16 + l16;
            s16x4 a0 = *(const s16x4*)&sVt[r * ATT_PAD + quad * 4];
            s16x4 a1 = *(const s16x4*)&sVt[r * ATT_PAD + 16 + quad * 4];
            s16x4 b0 = *(const s16x4*)&sVt[r * ATT_PAD + 32 + quad * 4];
            s16x4 b1 = *(const s16x4*)&sVt[r * ATT_PAD + 48 + quad * 4];
            s16x8 vf0, vf1;
#pragma unroll
            for (int j = 0; j < 4; ++j) {
                vf0[j] = a0[j]; vf0[4 + j] = a1[j];
                vf1[j] = b0[j]; vf1[4 + j] = b1[j];
            }
            acc[db] = __builtin_amdgcn_mfma_f32_16x16x32_bf16(pa0, vf0, acc[db], 0, 0, 0);
            acc[db] = __builtin_amdgcn_mfma_f32_16x16x32_bf16(pa1, vf1, acc[db], 0, 0, 0);
        }
    }

    float lq[4];
#pragma unroll
    for (int rg = 0; rg < 4; ++rg) lq[rg] = __shfl(l, quad * 4 + rg);
#pragma unroll
    for (int db = 0; db < 4; ++db) {
#pragma unroll
        for (int rg = 0; rg < 4; ++rg) {
            int row = qbase + w * 16 + quad * 4 + rg;
            y[((size_t)(b * Tn + row) * Hn + h) * HDn + db * 16 + l16] =
                f2bf(acc[db][rg] / lq[rg]);
        }
    }
}

// ---------------- launch ---------------------------------------------------------
extern "C" void kernel_launch(void* const* d_in, const int* in_sizes, int n_in,
                              void* d_out, int out_size, void* d_ws, size_t ws_size,
                              hipStream_t stream) {
    const float* x    = (const float*)d_in[0];
    const float* cosp = (const float*)d_in[1];
    const float* sinp = (const float*)d_in[2];
    const float* wq   = (const float*)d_in[3];
    const float* wk   = (const float*)d_in[4];
    const float* wv   = (const float*)d_in[5];
    const float* wo   = (const float*)d_in[6];
    const float* wfc  = (const float*)d_in[7];
    const float* wpr  = (const float*)d_in[8];
    const float* g1   = (const float*)d_in[9];
    const float* g2   = (const float*)d_in[10];
    float* out = (float*)d_out;

    const size_t S = (size_t)Bn * Tn * Cn;  // 3,145,728
    char* W = (char*)d_ws;
    // slot A (bf16, S elems): h -> yb -> h2 (sequentially dead)
    u16* slotA = (u16*)(W);                    // 2S bytes
    // slot B: qkv fp32 [M][2304] (12S bytes), later f bf16 [M][3072] (8S bytes)
    float* qkv = (float*)(W + 2 * S);
    u16* fbuf  = (u16*)(W + 2 * S);
    // slot C: x1 fp32 (4S bytes)
    float* x1  = (float*)(W + 14 * S);
    // weights bf16 at 18S
    u16* wt_qkv = (u16*)(W + 18 * S);                    // [2304][768]
    u16* wt_o   = wt_qkv + (size_t)QKVS * Cn;            // [768][768]
    u16* wt_fc  = wt_o + (size_t)Cn * Cn;                // [3072][768]
    u16* wt_pr  = wt_fc + (size_t)FFn * Cn;              // [768][3072]

    const int M = Bn * Tn;  // 4096

    // weight transposes (fp32 -> bf16, [K][N] -> [N][K])
    transpose_bf16_kernel<<<dim3(Cn / 32, Cn / 32), 256, 0, stream>>>(wq, wt_qkv, Cn, Cn);
    transpose_bf16_kernel<<<dim3(Cn / 32, Cn / 32), 256, 0, stream>>>(wk, wt_qkv + (size_t)Cn * Cn, Cn, Cn);
    transpose_bf16_kernel<<<dim3(Cn / 32, Cn / 32), 256, 0, stream>>>(wv, wt_qkv + (size_t)2 * Cn * Cn, Cn, Cn);
    transpose_bf16_kernel<<<dim3(Cn / 32, Cn / 32), 256, 0, stream>>>(wo, wt_o, Cn, Cn);
    transpose_bf16_kernel<<<dim3(FFn / 32, Cn / 32), 256, 0, stream>>>(wfc, wt_fc, Cn, FFn);
    transpose_bf16_kernel<<<dim3(Cn / 32, FFn / 32), 256, 0, stream>>>(wpr, wt_pr, FFn, Cn);

    // h = rmsnorm(x, g1) -> bf16
    rmsnorm_bf16_kernel<<<M, 256, 0, stream>>>(x, g1, slotA);

    // qkv = h @ [wq|wk|wv]  (fp32 out, fused N=2304)
    gemm_bt<0, 4><<<dim3(QKVS / 128, M / 128), 256, 0, stream>>>(slotA, wt_qkv, nullptr,
                                                                 qkv, M, QKVS, Cn);

    // RoPE in-place
    int nrope = Bn * Tn * Hn * D2n;
    rope_kernel<<<(nrope + 255) / 256, 256, 0, stream>>>(qkv, cosp, sinp, nrope);

    // attention -> y bf16 (slot A; h is dead)
    attn_mfma_kernel<<<Bn * Hn * (Tn / 64), 256, 0, stream>>>(qkv, slotA);

    // x1 = x + y @ wo   (fp32)
    gemm_bt<1, 2><<<dim3(Cn / 64, M / 128), 256, 0, stream>>>(slotA, wt_o, x, x1, M, Cn, Cn);

    // h2 = rmsnorm(x1, g2) -> bf16 (slot A; y is dead)
    rmsnorm_bf16_kernel<<<M, 256, 0, stream>>>(x1, g2, slotA);

    // f = relu(h2 @ wfc)^2 -> bf16 (slot B; qkv is dead)
    gemm_bt<2, 4><<<dim3(FFn / 128, M / 128), 256, 0, stream>>>(slotA, wt_fc, nullptr,
                                                                fbuf, M, FFn, Cn);

    // out = x1 + f @ wpr (fp32)
    gemm_bt<1, 2><<<dim3(Cn / 64, M / 128), 256, 0, stream>>>(fbuf, wt_pr, x1, out, M, Cn, FFn);
}

// Round 6
// 305.663 us; speedup vs baseline: 7.8242x; 1.2977x over previous
//
#include <hip/hip_runtime.h>
#include <hip/hip_bf16.h>
#include <math.h>

// Problem constants
#define Bn 2
#define Tn 2048
#define Cn 768
#define Hn 12
#define HDn 64
#define D2n 32
#define FFn 3072
#define EPSn 1e-5f
#define QKVS (3 * Cn)  // 2304

typedef short s16x8 __attribute__((ext_vector_type(8)));
typedef float f32x4 __attribute__((ext_vector_type(4)));
typedef unsigned short u16;

__device__ __forceinline__ u16 f2bf(float f) {
    union { float f; unsigned u; } v;
    v.f = f;
    unsigned r = (v.u + 0x7fffu + ((v.u >> 16) & 1u)) >> 16;
    return (u16)r;
}
__device__ __forceinline__ float bf2f(u16 u) {
    union { unsigned u; float f; } v;
    v.u = ((unsigned)u) << 16;
    return v.f;
}
__device__ __forceinline__ unsigned pack2(float a, float b) {
    union { float f; unsigned u; } va, vb;
    va.f = a; vb.f = b;
    return (va.u >> 16) | (vb.u & 0xffff0000u);  // trunc-to-bf16 pair
}

__device__ __forceinline__ void gl2lds16(const void* g, void* l) {
    __builtin_amdgcn_global_load_lds((const __attribute__((address_space(1))) void*)g,
                                     (__attribute__((address_space(3))) void*)l,
                                     16, 0, 0);
}

// ---------------- RMSNorm -> bf16 out: one block per row ------------------------
__global__ __launch_bounds__(256) void rmsnorm_bf16_kernel(const float* __restrict__ x,
                                                           const float* __restrict__ g,
                                                           u16* __restrict__ out) {
    int row = blockIdx.x;
    const float* xr = x + (size_t)row * Cn;
    u16* orow = out + (size_t)row * Cn;
    int tid = threadIdx.x;
    float v[3];
    float ss = 0.f;
#pragma unroll
    for (int i = 0; i < 3; ++i) {
        v[i] = xr[tid + 256 * i];
        ss += v[i] * v[i];
    }
#pragma unroll
    for (int o = 32; o; o >>= 1) ss += __shfl_xor(ss, o);
    __shared__ float red[4];
    int w = tid >> 6;
    if ((tid & 63) == 0) red[w] = ss;
    __syncthreads();
    float tot = red[0] + red[1] + red[2] + red[3];
    float s = rsqrtf(tot / (float)Cn + EPSn);
#pragma unroll
    for (int i = 0; i < 3; ++i) {
        int c = tid + 256 * i;
        orow[c] = f2bf(g[c] * v[i] * s);
    }
}

// ---------------- Weight transpose+convert: W[K][N] fp32 -> Wt[N][K] bf16 --------
__global__ __launch_bounds__(256) void transpose_bf16_kernel(const float* __restrict__ W,
                                                             u16* __restrict__ Wt,
                                                             int K, int N) {
    __shared__ u16 t[32][33];
    int bx = blockIdx.x * 32;
    int by = blockIdx.y * 32;
    int tx = threadIdx.x & 31, ty = threadIdx.x >> 5;
#pragma unroll
    for (int i = 0; i < 4; ++i) {
        int kk = by + ty + i * 8;
        t[ty + i * 8][tx] = f2bf(W[(size_t)kk * N + bx + tx]);
    }
    __syncthreads();
#pragma unroll
    for (int i = 0; i < 4; ++i) {
        int n = bx + ty + i * 8;
        Wt[(size_t)n * K + by + tx] = t[tx][ty + i * 8];
    }
}

// ---------------- bf16 MFMA GEMM: C[M][N] = A[M][K] @ Bt[N][K]^T (+ epilogue) ----
// EPI: 0 = fp32, 1 = fp32 + fp32 residual, 2 = relu^2 -> bf16, 3 = bf16
template <int EPI, int NI>
__global__ __launch_bounds__(256) void gemm_bt(const u16* __restrict__ A,
                                               const u16* __restrict__ Bt,
                                               const float* __restrict__ R,
                                               void* __restrict__ Cout,
                                               int M, int N, int K) {
    __shared__ u16 As[128 * 32];
    __shared__ u16 Bs[NI * 32 * 32];
    int tid = threadIdx.x;
    int w = tid >> 6, lane = tid & 63;
    int quad = lane >> 4, l16 = lane & 15;
    int bm = blockIdx.y * 128;
    int bn = blockIdx.x * (NI * 32);
    int wrow = (w & 1) * 64, wcol = (w >> 1) * (NI * 16);

    f32x4 acc[4][NI];
#pragma unroll
    for (int i = 0; i < 4; ++i)
#pragma unroll
        for (int j = 0; j < NI; ++j) acc[i][j] = (f32x4){0.f, 0.f, 0.f, 0.f};

    int srow = lane >> 2;
    int scol = (lane & 3) * 8;

    for (int k0 = 0; k0 < K; k0 += 32) {
        __syncthreads();
#pragma unroll
        for (int r = 0; r < 2; ++r) {
            int row = r * 64 + w * 16 + srow;
            gl2lds16(A + (size_t)(bm + row) * K + k0 + scol, &As[(r * 64 + w * 16) * 32]);
        }
#pragma unroll
        for (int r = 0; r < NI / 2; ++r) {
            int row = r * 64 + w * 16 + srow;
            gl2lds16(Bt + (size_t)(bn + row) * K + k0 + scol, &Bs[(r * 64 + w * 16) * 32]);
        }
        __syncthreads();

        s16x8 af[4], bf[NI];
#pragma unroll
        for (int mi = 0; mi < 4; ++mi)
            af[mi] = *(const s16x8*)&As[(wrow + mi * 16 + l16) * 32 + quad * 8];
#pragma unroll
        for (int ni = 0; ni < NI; ++ni)
            bf[ni] = *(const s16x8*)&Bs[(wcol + ni * 16 + l16) * 32 + quad * 8];
#pragma unroll
        for (int mi = 0; mi < 4; ++mi)
#pragma unroll
            for (int ni = 0; ni < NI; ++ni)
                acc[mi][ni] = __builtin_amdgcn_mfma_f32_16x16x32_bf16(af[mi], bf[ni],
                                                                      acc[mi][ni], 0, 0, 0);
    }

#pragma unroll
    for (int mi = 0; mi < 4; ++mi) {
#pragma unroll
        for (int rg = 0; rg < 4; ++rg) {
            size_t row = bm + wrow + mi * 16 + quad * 4 + rg;
#pragma unroll
            for (int ni = 0; ni < NI; ++ni) {
                size_t idx = row * N + bn + wcol + ni * 16 + l16;
                float c = acc[mi][ni][rg];
                if (EPI == 0) {
                    ((float*)Cout)[idx] = c;
                } else if (EPI == 1) {
                    ((float*)Cout)[idx] = c + R[idx];
                } else if (EPI == 2) {
                    c = fmaxf(c, 0.f);
                    ((u16*)Cout)[idx] = f2bf(c * c);
                } else {
                    ((u16*)Cout)[idx] = f2bf(c);
                }
            }
        }
    }
}

// ---------------- Prep: RoPE + relayout to attention-friendly bf16 buffers -------
// In: qkvb bf16 [b*T][2304]. Out: qh [bh][t][64] (x0.125), kh [bh][t][64],
// vtp [bh][d][key] with each 64-key chunk's keys permuted to PV-fragment order:
// 16B block s of chunk: h2=s>>2, q=s&3; elem e<4 -> key 32*h2+q*4+e,
// e>=4 -> key 32*h2+16+q*4+(e-4).
__global__ __launch_bounds__(256) void rope_prep_kernel(const u16* __restrict__ qkvb,
                                                        const float* __restrict__ cosp,
                                                        const float* __restrict__ sinp,
                                                        u16* __restrict__ qh,
                                                        u16* __restrict__ kh,
                                                        u16* __restrict__ vtp) {
    __shared__ u16 sT[64][72];
    int tc = blockIdx.x, bh = blockIdx.y;
    int h = bh % Hn, b = bh / Hn;
    int t0 = tc * 64;
    int tid = threadIdx.x;

    // --- Q/K rope: thread = (row r, 8-col group c) ---
    int r = tid >> 2;
    int c = (tid & 3) * 8;
    int t = t0 + r;
    size_t srow = (size_t)(b * Tn + t) * QKVS + h * HDn;
    float4 c0 = *(const float4*)&cosp[t * D2n + c];
    float4 c1 = *(const float4*)&cosp[t * D2n + c + 4];
    float4 s0 = *(const float4*)&sinp[t * D2n + c];
    float4 s1 = *(const float4*)&sinp[t * D2n + c + 4];
    float cs[8] = {c0.x, c0.y, c0.z, c0.w, c1.x, c1.y, c1.z, c1.w};
    float sn[8] = {s0.x, s0.y, s0.z, s0.w, s1.x, s1.y, s1.z, s1.w};
#pragma unroll
    for (int tens = 0; tens < 2; ++tens) {  // 0 = q (scaled), 1 = k
        size_t off = srow + tens * Cn;
        float sc = tens ? 1.f : 0.125f;
        ushort4 lo0 = *(const ushort4*)&qkvb[off + c];
        ushort4 lo1 = *(const ushort4*)&qkvb[off + c + 4];
        ushort4 hi0 = *(const ushort4*)&qkvb[off + c + 32];
        ushort4 hi1 = *(const ushort4*)&qkvb[off + c + 36];
        u16 lo[8] = {lo0.x, lo0.y, lo0.z, lo0.w, lo1.x, lo1.y, lo1.z, lo1.w};
        u16 hi[8] = {hi0.x, hi0.y, hi0.z, hi0.w, hi1.x, hi1.y, hi1.z, hi1.w};
        u16 o1[8], o2[8];
#pragma unroll
        for (int j = 0; j < 8; ++j) {
            float x1 = bf2f(lo[j]), x2 = bf2f(hi[j]);
            o1[j] = f2bf((x1 * cs[j] + x2 * sn[j]) * sc);
            o2[j] = f2bf((-x1 * sn[j] + x2 * cs[j]) * sc);
        }
        u16* dst = (tens ? kh : qh) + ((size_t)bh * Tn + t) * HDn;
        *(ushort4*)&dst[c]      = make_ushort4(o1[0], o1[1], o1[2], o1[3]);
        *(ushort4*)&dst[c + 4]  = make_ushort4(o1[4], o1[5], o1[6], o1[7]);
        *(ushort4*)&dst[c + 32] = make_ushort4(o2[0], o2[1], o2[2], o2[3]);
        *(ushort4*)&dst[c + 36] = make_ushort4(o2[4], o2[5], o2[6], o2[7]);
    }

    // --- V: LDS transpose + permuted write ---
    int r2 = tid >> 2;
    int cc = (tid & 3) * 16;
    size_t vrow = (size_t)(b * Tn + t0 + r2) * QKVS + h * HDn + 2 * Cn;
#pragma unroll
    for (int j = 0; j < 4; ++j)
        *(ushort4*)&sT[r2][cc + j * 4] = *(const ushort4*)&qkvb[vrow + cc + j * 4];
    __syncthreads();
    int d = tid >> 2;
#pragma unroll
    for (int p = 0; p < 2; ++p) {
        int s = (tid & 3) + p * 4;
        int h2 = s >> 2, qq = s & 3;
        u16 e[8];
#pragma unroll
        for (int j = 0; j < 4; ++j) e[j] = sT[32 * h2 + qq * 4 + j][d];
#pragma unroll
        for (int j = 0; j < 4; ++j) e[4 + j] = sT[32 * h2 + 16 + qq * 4 + j][d];
        size_t outb = ((size_t)bh * HDn + d) * Tn + t0 + s * 8;
        *(ushort4*)&vtp[outb]     = make_ushort4(e[0], e[1], e[2], e[3]);
        *(ushort4*)&vtp[outb + 4] = make_ushort4(e[4], e[5], e[6], e[7]);
    }
}

// ---------------- MFMA causal flash attention v3 ---------------------------------
// R3's proven structure (plain vector loads + ds_write_b128, padded LDS, two
// uniform barriers). bf16 pre-roped inputs, pre-permuted V^T, Q pre-scaled.
#define APAD 72  // row stride (u16): 144 B = 16B-aligned, 4-bank rotation/row

__global__ __launch_bounds__(256) void attn_v3_kernel(const u16* __restrict__ qh,
                                                      const u16* __restrict__ kh,
                                                      const u16* __restrict__ vtp,
                                                      u16* __restrict__ y) {
    __shared__ u16 sQ[64 * APAD];
    __shared__ u16 sK[64 * APAD];
    __shared__ u16 sVp[64 * APAD];

    int qt = 31 - (blockIdx.x / 24);  // LPT: heaviest query tiles first
    int bh = blockIdx.x % 24;
    int h = bh % Hn, b = bh / Hn;
    int qbase = qt * 64;
    int tid = threadIdx.x;
    int lane = tid & 63, w = tid >> 6;
    int quad = lane >> 4, l16 = lane & 15;

    const u16* qg = qh + (size_t)bh * Tn * HDn;
    const u16* kg = kh + (size_t)bh * Tn * HDn;
    const u16* vg = vtp + (size_t)bh * HDn * Tn;  // [d][t]

    // stage Q tile: 512 x 16B blocks; idx -> row=idx>>3, blk=idx&7 (coalesced)
#pragma unroll
    for (int i = 0; i < 2; ++i) {
        int idx = tid + 256 * i;
        int row = idx >> 3, blk = idx & 7;
        *(s16x8*)&sQ[row * APAD + blk * 8] =
            *(const s16x8*)&qg[(size_t)(qbase + row) * HDn + blk * 8];
    }
    __syncthreads();

    // Q fragment (B operand of S^T): wave w uses its own 16 query rows
    s16x8 qf0 = *(const s16x8*)&sQ[(w * 16 + l16) * APAD + quad * 8];
    s16x8 qf1 = *(const s16x8*)&sQ[(w * 16 + l16) * APAD + 32 + quad * 8];

    f32x4 acc[4];
#pragma unroll
    for (int i = 0; i < 4; ++i) acc[i] = (f32x4){0.f, 0.f, 0.f, 0.f};
    float m = -3e38f, l = 0.f;
    const int qloc = w * 16 + l16;

    for (int kbase = 0; kbase <= qbase; kbase += 64) {
        __syncthreads();  // prior chunk's LDS reads complete before restage
#pragma unroll
        for (int i = 0; i < 2; ++i) {
            int idx = tid + 256 * i;
            int row = idx >> 3, blk = idx & 7;
            *(s16x8*)&sK[row * APAD + blk * 8] =
                *(const s16x8*)&kg[(size_t)(kbase + row) * HDn + blk * 8];
            *(s16x8*)&sVp[row * APAD + blk * 8] =
                *(const s16x8*)&vg[(size_t)row * Tn + kbase + blk * 8];
        }
        __syncthreads();

        const bool diag = (kbase == qbase);

        // S^T = K @ Q^T (Q pre-scaled): C[key_local=kb*16+quad*4+rg][query=l16]
        f32x4 st[4];
#pragma unroll
        for (int kb = 0; kb < 4; ++kb) {
            s16x8 kf0 = *(const s16x8*)&sK[(kb * 16 + l16) * APAD + quad * 8];
            s16x8 kf1 = *(const s16x8*)&sK[(kb * 16 + l16) * APAD + 32 + quad * 8];
            f32x4 cfr = (f32x4){0.f, 0.f, 0.f, 0.f};
            cfr = __builtin_amdgcn_mfma_f32_16x16x32_bf16(kf0, qf0, cfr, 0, 0, 0);
            cfr = __builtin_amdgcn_mfma_f32_16x16x32_bf16(kf1, qf1, cfr, 0, 0, 0);
            st[kb] = cfr;
        }

        if (diag) {
#pragma unroll
            for (int kb = 0; kb < 4; ++kb)
#pragma unroll
                for (int rg = 0; rg < 4; ++rg)
                    if (kb * 16 + quad * 4 + rg > qloc) st[kb][rg] = -1e30f;
        }

        // online softmax per query (= lane l16, replicated across quads)
        float mx = -3e38f;
#pragma unroll
        for (int kb = 0; kb < 4; ++kb)
#pragma unroll
            for (int rg = 0; rg < 4; ++rg) mx = fmaxf(mx, st[kb][rg]);
        mx = fmaxf(mx, __shfl_xor(mx, 16));
        mx = fmaxf(mx, __shfl_xor(mx, 32));
        float mnew = fmaxf(m, mx);
        float alpha = __expf(m - mnew);
        m = mnew;
        float tsum = 0.f;
#pragma unroll
        for (int kb = 0; kb < 4; ++kb) {
#pragma unroll
            for (int rg = 0; rg < 4; ++rg) {
                float p = __expf(st[kb][rg] - mnew);
                st[kb][rg] = p;
                tsum += p;
            }
        }
        tsum += __shfl_xor(tsum, 16);
        tsum += __shfl_xor(tsum, 32);
        l = l * alpha + tsum;

        float aq[4];
#pragma unroll
        for (int rg = 0; rg < 4; ++rg) aq[rg] = __shfl(alpha, quad * 4 + rg);
#pragma unroll
        for (int db = 0; db < 4; ++db)
#pragma unroll
            for (int rg = 0; rg < 4; ++rg) acc[db][rg] *= aq[rg];

        // P fragments straight from registers (trunc pack); element order matches
        // the prep-side V permutation.
        union { s16x8 v; unsigned u[4]; } pa0, pa1;
        pa0.u[0] = pack2(st[0][0], st[0][1]);
        pa0.u[1] = pack2(st[0][2], st[0][3]);
        pa0.u[2] = pack2(st[1][0], st[1][1]);
        pa0.u[3] = pack2(st[1][2], st[1][3]);
        pa1.u[0] = pack2(st[2][0], st[2][1]);
        pa1.u[1] = pack2(st[2][2], st[2][3]);
        pa1.u[2] = pack2(st[3][0], st[3][1]);
        pa1.u[3] = pack2(st[3][2], st[3][3]);

        // O += P @ V : V frags are contiguous 16B blocks (pre-permuted)
#pragma unroll
        for (int db = 0; db < 4; ++db) {
            int rr = db * 16 + l16;
            s16x8 vf0 = *(const s16x8*)&sVp[rr * APAD + quad * 8];
            s16x8 vf1 = *(const s16x8*)&sVp[rr * APAD + 32 + quad * 8];
            acc[db] = __builtin_amdgcn_mfma_f32_16x16x32_bf16(pa0.v, vf0, acc[db], 0, 0, 0);
            acc[db] = __builtin_amdgcn_mfma_f32_16x16x32_bf16(pa1.v, vf1, acc[db], 0, 0, 0);
        }
    }

    // epilogue: row = qbase + w*16 + quad*4 + rg, col = db*16 + l16
    float lq[4];
#pragma unroll
    for (int rg = 0; rg < 4; ++rg) lq[rg] = __shfl(l, quad * 4 + rg);
#pragma unroll
    for (int db = 0; db < 4; ++db) {
#pragma unroll
        for (int rg = 0; rg < 4; ++rg) {
            int row = qbase + w * 16 + quad * 4 + rg;
            y[((size_t)(b * Tn + row) * Hn + h) * HDn + db * 16 + l16] =
                f2bf(acc[db][rg] / lq[rg]);
        }
    }
}

// ---------------- launch ---------------------------------------------------------
extern "C" void kernel_launch(void* const* d_in, const int* in_sizes, int n_in,
                              void* d_out, int out_size, void* d_ws, size_t ws_size,
                              hipStream_t stream) {
    const float* x    = (const float*)d_in[0];
    const float* cosp = (const float*)d_in[1];
    const float* sinp = (const float*)d_in[2];
    const float* wq   = (const float*)d_in[3];
    const float* wk   = (const float*)d_in[4];
    const float* wv   = (const float*)d_in[5];
    const float* wo   = (const float*)d_in[6];
    const float* wfc  = (const float*)d_in[7];
    const float* wpr  = (const float*)d_in[8];
    const float* g1   = (const float*)d_in[9];
    const float* g2   = (const float*)d_in[10];
    float* out = (float*)d_out;

    const size_t S = (size_t)Bn * Tn * Cn;  // elems
    char* W = (char*)d_ws;
    u16* slotA = (u16*)W;                   // [0,2S): h, then h2
    u16* qkvb  = (u16*)(W + 2 * S);         // [2S,8S): qkv bf16 [M][2304]
    u16* yh    = (u16*)(W + 2 * S);         // [2S,4S): y bf16 (after prep)
    u16* fbuf  = (u16*)(W + 4 * S);         // [4S,12S): FF bf16 [M][3072]
    u16* qhb   = (u16*)(W + 8 * S);         // [8S,10S)
    u16* khb   = (u16*)(W + 10 * S);        // [10S,12S)
    u16* vtpb  = (u16*)(W + 12 * S);        // [12S,14S)
    float* x1  = (float*)(W + 14 * S);      // [14S,18S)
    u16* wt_qkv = (u16*)(W + 18 * S);
    u16* wt_o   = wt_qkv + (size_t)QKVS * Cn;
    u16* wt_fc  = wt_o + (size_t)Cn * Cn;
    u16* wt_pr  = wt_fc + (size_t)FFn * Cn;

    const int M = Bn * Tn;  // 4096

    transpose_bf16_kernel<<<dim3(Cn / 32, Cn / 32), 256, 0, stream>>>(wq, wt_qkv, Cn, Cn);
    transpose_bf16_kernel<<<dim3(Cn / 32, Cn / 32), 256, 0, stream>>>(wk, wt_qkv + (size_t)Cn * Cn, Cn, Cn);
    transpose_bf16_kernel<<<dim3(Cn / 32, Cn / 32), 256, 0, stream>>>(wv, wt_qkv + (size_t)2 * Cn * Cn, Cn, Cn);
    transpose_bf16_kernel<<<dim3(Cn / 32, Cn / 32), 256, 0, stream>>>(wo, wt_o, Cn, Cn);
    transpose_bf16_kernel<<<dim3(FFn / 32, Cn / 32), 256, 0, stream>>>(wfc, wt_fc, Cn, FFn);
    transpose_bf16_kernel<<<dim3(Cn / 32, FFn / 32), 256, 0, stream>>>(wpr, wt_pr, FFn, Cn);

    rmsnorm_bf16_kernel<<<M, 256, 0, stream>>>(x, g1, slotA);

    // qkv = h @ [wq|wk|wv] -> bf16
    gemm_bt<3, 4><<<dim3(QKVS / 128, M / 128), 256, 0, stream>>>(slotA, wt_qkv, nullptr,
                                                                 qkvb, M, QKVS, Cn);

    // rope + relayout to head-major bf16 (+ V transpose/permute)
    rope_prep_kernel<<<dim3(Tn / 64, Bn * Hn), 256, 0, stream>>>(qkvb, cosp, sinp,
                                                                 qhb, khb, vtpb);

    // attention -> y bf16 [b,t,h,d]
    attn_v3_kernel<<<Bn * Hn * (Tn / 64), 256, 0, stream>>>(qhb, khb, vtpb, yh);

    // x1 = x + y @ wo
    gemm_bt<1, 2><<<dim3(Cn / 64, M / 128), 256, 0, stream>>>(yh, wt_o, x, x1, M, Cn, Cn);

    rmsnorm_bf16_kernel<<<M, 256, 0, stream>>>(x1, g2, slotA);

    // f = relu(h2 @ wfc)^2 -> bf16
    gemm_bt<2, 4><<<dim3(FFn / 128, M / 128), 256, 0, stream>>>(slotA, wt_fc, nullptr,
                                                                fbuf, M, FFn, Cn);

    // out = x1 + f @ wpr
    gemm_bt<1, 2><<<dim3(Cn / 64, M / 128), 256, 0, stream>>>(fbuf, wt_pr, x1, out, M, Cn, FFn);
}